// Round 6
// baseline (545.081 us; speedup 1.0000x reference)
//
#include <hip/hip_runtime.h>

// VQ nearest-neighbor: N=65536 rows (D=256) vs K=1024 codes.
// Outputs (f32, concat): emb_out [N*D], ids [N], loss [N].
// Round 6 == round 5 resubmit (round 5 hit an infra failure, never ran):
// 8x8 register tile (round-4's 8x16 spilled: VGPR=128 with a 128-float acc ->
// scratch, VALUBusy 53%->9.5%). KEEP the XOR quad-swizzle (conflicts
// 9.2e7 -> 0) and the fused epilogue. Inner FMA expressed on float2 columns
// via __builtin_elementwise_fma: if gfx950 v_pk_fma_f32 is dual-rate this
// halves the FMA floor; otherwise neutral (identical numerics).

typedef float f32x2 __attribute__((ext_vector_type(2)));

constexpr int NROWS = 65536;
constexpr int DDIM  = 256;
constexpr int KCB   = 1024;
constexpr int BM    = 128;    // rows per block
constexpr int BN    = 128;    // codes per tile
constexpr int DKC   = 32;     // d-chunk staged in LDS
constexpr float COMMIT_W = 0.25f;
constexpr float BIG = 3.402823466e+38f;

__global__ void cnorm_k(const float* __restrict__ cb, float* __restrict__ cn) {
    int k    = blockIdx.x * 4 + (threadIdx.x >> 6);   // one wave per code
    int lane = threadIdx.x & 63;
    float4 v = *reinterpret_cast<const float4*>(cb + (size_t)k * DDIM + lane * 4);
    float s = v.x * v.x + v.y * v.y + v.z * v.z + v.w * v.w;
    #pragma unroll
    for (int off = 32; off; off >>= 1) s += __shfl_xor(s, off);
    if (lane == 0) cn[k] = s;
}

__launch_bounds__(256, 2)
__global__ void vq_k(const float* __restrict__ x, const float* __restrict__ cb,
                     const float* __restrict__ cn, float* __restrict__ out) {
    // [d][item], quad-swizzled: phys quad = logical quad ^ ((d>>2)&7).
    __shared__ __align__(16) float Xs[DKC * BM];
    __shared__ __align__(16) float Cs[DKC * BN];
    __shared__ int bestiS[BM];

    const int tid  = threadIdx.x;
    const int n0   = blockIdx.x * BM;
    const int ty   = tid >> 4;        // owns rows ty*8..+7
    const int tx   = tid & 15;        // owns cols tx*8..+7 within tile
    const int sg   = tid & 7;         // staging d-quad group == (d>>2)&7
    const int scol = sg << 2;
    const int srow = tid >> 3;        // 0..31

    float rbv[8]; int rbi[8];
    #pragma unroll
    for (int i = 0; i < 8; ++i) { rbv[i] = BIG; rbi[i] = 0; }

    #pragma unroll 1
    for (int ct = 0; ct < KCB / BN; ++ct) {
        f32x2 acc[8][4];                       // 8 rows x 8 cols (4 float2)
        #pragma unroll
        for (int i = 0; i < 8; ++i)
            #pragma unroll
            for (int m = 0; m < 4; ++m) acc[i][m] = (f32x2){0.f, 0.f};

        #pragma unroll 1
        for (int d0 = 0; d0 < DDIM; d0 += DKC) {
            __syncthreads();   // protect LDS vs previous chunk's readers
            #pragma unroll
            for (int it = 0; it < 4; ++it) {           // X: 128 rows x 32 d
                int r  = srow + it * 32;
                int pq = ((((r >> 2) ^ sg) << 2) | (r & 3));
                float4 v = *reinterpret_cast<const float4*>(
                    x + (size_t)(n0 + r) * DDIM + d0 + scol);
                Xs[(scol + 0) * BM + pq] = v.x;
                Xs[(scol + 1) * BM + pq] = v.y;
                Xs[(scol + 2) * BM + pq] = v.z;
                Xs[(scol + 3) * BM + pq] = v.w;
            }
            #pragma unroll
            for (int it = 0; it < 4; ++it) {           // C: 128 codes x 32 d
                int r  = srow + it * 32;
                int pq = ((((r >> 2) ^ sg) << 2) | (r & 3));
                float4 v = *reinterpret_cast<const float4*>(
                    cb + (size_t)(ct * BN + r) * DDIM + d0 + scol);
                Cs[(scol + 0) * BN + pq] = v.x;
                Cs[(scol + 1) * BN + pq] = v.y;
                Cs[(scol + 2) * BN + pq] = v.z;
                Cs[(scol + 3) * BN + pq] = v.w;
            }
            __syncthreads();
            #pragma unroll 1
            for (int dq = 0; dq < 8; ++dq) {           // d-quads
                const int xrow = dq * 4 * BM;
                const int crow = dq * 4 * BN;
                const int xq0  = ((ty * 2    ) ^ dq) << 2;
                const int xq1  = ((ty * 2 + 1) ^ dq) << 2;
                const int cq0  = ((tx * 2    ) ^ dq) << 2;
                const int cq1  = ((tx * 2 + 1) ^ dq) << 2;
                #pragma unroll
                for (int dd = 0; dd < 4; ++dd) {
                    float4 xa = *reinterpret_cast<const float4*>(&Xs[xrow + dd * BM + xq0]);
                    float4 xb = *reinterpret_cast<const float4*>(&Xs[xrow + dd * BM + xq1]);
                    float4 ca = *reinterpret_cast<const float4*>(&Cs[crow + dd * BN + cq0]);
                    float4 cc = *reinterpret_cast<const float4*>(&Cs[crow + dd * BN + cq1]);
                    float xr[8]  = {xa.x, xa.y, xa.z, xa.w, xb.x, xb.y, xb.z, xb.w};
                    f32x2 cp[4]  = {{ca.x, ca.y}, {ca.z, ca.w}, {cc.x, cc.y}, {cc.z, cc.w}};
                    #pragma unroll
                    for (int i = 0; i < 8; ++i) {
                        f32x2 xv2 = {xr[i], xr[i]};
                        #pragma unroll
                        for (int m = 0; m < 4; ++m)
                            acc[i][m] = __builtin_elementwise_fma(xv2, cp[m], acc[i][m]);
                    }
                }
            }
        }
        // fused argmin over this 128-code tile (registers + shuffles only)
        float4 cna = *reinterpret_cast<const float4*>(&cn[ct * BN + tx * 8]);
        float4 cnb = *reinterpret_cast<const float4*>(&cn[ct * BN + tx * 8 + 4]);
        float cnv[8] = {cna.x, cna.y, cna.z, cna.w, cnb.x, cnb.y, cnb.z, cnb.w};
        #pragma unroll
        for (int i = 0; i < 8; ++i) {
            float bv = BIG; int bi = 0;
            #pragma unroll
            for (int j = 0; j < 8; ++j) {              // j ascending == col ascending
                float v  = cnv[j] - 2.0f * acc[i][j >> 1][j & 1];
                int col  = ct * BN + tx * 8 + j;
                if (v < bv) { bv = v; bi = col; }      // strict < keeps first min
            }
            #pragma unroll
            for (int off = 1; off < 16; off <<= 1) {   // reduce across 16 tx-lanes
                float v2 = __shfl_xor(bv, off);
                int   i2 = __shfl_xor(bi, off);
                if (v2 < bv || (v2 == bv && i2 < bi)) { bv = v2; bi = i2; }
            }
            if (bv < rbv[i]) { rbv[i] = bv; rbi[i] = bi; }  // earlier ct wins ties
        }
    }
    if (tx == 0) {
        #pragma unroll
        for (int i = 0; i < 8; ++i) bestiS[ty * 8 + i] = rbi[i];
    }
    __syncthreads();

    // fused epilogue: gather code row -> emb, ids, loss = 1.25*||x-c||^2
    float* emb = out;                            // [N*D]
    float* ido = out + (size_t)NROWS * DDIM;     // [N]
    float* lss = ido + NROWS;                    // [N]
    const int wv = tid >> 6, lane = tid & 63;    // one wave per 32 rows
    for (int r = wv * 32; r < wv * 32 + 32; ++r) {
        int bid = bestiS[r];
        int bc  = bid < 0 ? 0 : (bid > KCB - 1 ? KCB - 1 : bid);
        float4 xv = *reinterpret_cast<const float4*>(x  + (size_t)(n0 + r) * DDIM + lane * 4);
        float4 cv = *reinterpret_cast<const float4*>(cb + (size_t)bc  * DDIM + lane * 4);
        *reinterpret_cast<float4*>(emb + (size_t)(n0 + r) * DDIM + lane * 4) = cv;
        float dx = xv.x - cv.x, dy = xv.y - cv.y;
        float dz = xv.z - cv.z, dw = xv.w - cv.w;
        float s = dx * dx + dy * dy + dz * dz + dw * dw;
        #pragma unroll
        for (int off = 32; off; off >>= 1) s += __shfl_xor(s, off);
        if (lane == 0) {
            lss[n0 + r] = (1.0f + COMMIT_W) * s;
            ido[n0 + r] = (float)bid;
        }
    }
}

extern "C" void kernel_launch(void* const* d_in, const int* in_sizes, int n_in,
                              void* d_out, int out_size, void* d_ws, size_t ws_size,
                              hipStream_t stream) {
    const float* x  = (const float*)d_in[0];
    const float* cb = (const float*)d_in[1];
    if (n_in >= 2 && in_sizes[0] < in_sizes[1]) {   // guard input ordering
        x  = (const float*)d_in[1];
        cb = (const float*)d_in[0];
    }
    float* cn  = (float*)d_ws;                      // [1024] f32
    float* out = (float*)d_out;

    cnorm_k<<<KCB / 4,    256, 0, stream>>>(cb, cn);
    vq_k   <<<NROWS / BM, 256, 0, stream>>>(x, cb, cn, out);
}